// Round 11
// baseline (674.986 us; speedup 1.0000x reference)
//
#include <hip/hip_runtime.h>
#include <hip/hip_cooperative_groups.h>
#include <math.h>

namespace cg = cooperative_groups;

// Top-1 MoE as ONE cooperative persistent kernel, 5 grid.sync phases:
//  A: x->xh/xl convert, gw1 hi/lo transpose, counts zero
//  B: gate partial GEMM tiles + all expert-weight transposes (independent fill)
//  C: finalize (logits/softmax/argmax/scatter; hp read direct from global)
//  D: gemm1 (experts 0/1 up-proj, 64x64 tiles)
//  E: gemm2 (down-proj) + cheap experts 2..5
// Rationale (r10): ~110us of 298 was inter-dispatch boundaries + tail drains.

#define E 1024
#define GH 256
#define NEXP 6
#define NTOK 8192

typedef __attribute__((ext_vector_type(8))) short bf16x8;
typedef __attribute__((ext_vector_type(4))) float f32x4;

__device__ __forceinline__ float gelu_erf(float v) {
    return 0.5f * v * (1.0f + erff(v * 0.70710678118654752440f));
}

__device__ __forceinline__ unsigned short f2bf(float f) {
    union { float f; unsigned u; } c; c.f = f;
    unsigned u = c.u;
    u += 0x7fffu + ((u >> 16) & 1u);   // RNE
    return (unsigned short)(u >> 16);
}

__device__ __forceinline__ float bf2f(unsigned short h) {
    union { unsigned u; float f; } c; c.u = ((unsigned)h) << 16;
    return c.f;
}

__device__ __forceinline__ float dot4(float4 a, float4 b) {
    return a.x * b.x + a.y * b.y + a.z * b.z + a.w * b.w;
}

// LDS tile addressing (ushort units): row stride 32 (=64B), k-group XOR swizzle.
__device__ __forceinline__ int ldso(int row, int q) {
    return row * 32 + ((q ^ ((row >> 1) & 3)) << 3);
}

struct MoeParams {
    const float *x, *gw1, *gb1, *gw2, *gb2, *ebias, *pm_alpha;
    const float *dfc_w, *dfc_b, *dproj_w, *dproj_b;
    const float *sfc_w, *sfc_b, *sproj_w, *sproj_b;
    const float *p2_w, *p2_v, *p2_alpha, *p2_b, *p2_bias;
    const float *p4_w, *p4_v, *p4_alpha, *p4_b, *p4_bias;
    const float *rg_u, *rg_a, *rg_b, *rg_bias;
    const float *fl_dw, *fl_db, *fl_uw, *fl_ub;
    float* out;
    int* counts; float* scale; int* tlist; int* eid; float* fl_dwT;
    unsigned short *w1cat, *dfc_wt, *dpj_wt, *sfc_wt, *spj_wt, *x_hi, *x_lo;
    float *hp0, *hp1;
    unsigned short *h1, *h2;
};

__global__ __launch_bounds__(256, 4)
void moe_mega_kernel(MoeParams P) {
    cg::grid_group grid = cg::this_grid();
    __shared__ __align__(16) char smem[12544];
    const int tid  = threadIdx.x;
    const int nb   = gridDim.x;
    const int lane = tid & 63, wvi = tid >> 6;

    //================ Phase A: convert + w1cat + zero counts ================
    if (blockIdx.x == 0 && tid < 64) P.counts[tid] = 0;
    {
        float (*tile)[33] = (float (*)[33])smem;
        const int tx = tid & 31, ty = tid >> 5;
        for (int u = blockIdx.x; u < 2304; u += nb) {
            if (u < 2048) {
                const int base = u * 1024 + tid;
#pragma unroll
                for (int ii = 0; ii < 4; ++ii) {
                    const int i = base + ii * 256;
                    float4 v = reinterpret_cast<const float4*>(P.x)[i];
                    ushort4 h, l;
                    h.x = f2bf(v.x); l.x = f2bf(v.x - bf2f(h.x));
                    h.y = f2bf(v.y); l.y = f2bf(v.y - bf2f(h.y));
                    h.z = f2bf(v.z); l.z = f2bf(v.z - bf2f(h.z));
                    h.w = f2bf(v.w); l.w = f2bf(v.w - bf2f(h.w));
                    reinterpret_cast<ushort4*>(P.x_hi)[i] = h;
                    reinterpret_cast<ushort4*>(P.x_lo)[i] = l;
                }
            } else {
                const int b = u - 2048;
                const int c0 = (b & 7) * 32, r0 = (b >> 3) * 32;
                __syncthreads();
#pragma unroll
                for (int i = 0; i < 4; ++i)
                    tile[ty + i * 8][tx] = P.gw1[(size_t)(r0 + ty + i * 8) * GH + c0 + tx];
                __syncthreads();
#pragma unroll
                for (int i = 0; i < 4; ++i) {
                    float v = tile[tx][ty + i * 8];
                    unsigned short h = f2bf(v);
                    size_t row = (size_t)(c0 + ty + i * 8) * 2048;
                    P.w1cat[row + r0 + tx] = h;
                    P.w1cat[row + 1024 + r0 + tx] = f2bf(v - bf2f(h));
                }
            }
        }
    }
    grid.sync();

    //====== Phase B: gate partial tiles (512) + weight transposes (6208) ======
    {
        const int wm = (wvi & 1) * 64, wn = (wvi >> 1) * 32;
        const int lm = lane & 15, q = lane >> 4;
        const int r0t = tid >> 2, gsl = tid & 3;
        const int g = gsl ^ ((r0t >> 1) & 3);
        unsigned short* As = (unsigned short*)smem;       // 128x32
        unsigned short* Bs = As + 128 * 32;               // 64x32
        float (*tile)[33] = (float (*)[33])smem;
        const int tx = tid & 31, ty = tid >> 5;
        for (int u = blockIdx.x; u < 6720; u += nb) {
            if (u < 512) {
                const int z = u >> 8, r = u & 255;
                const int n0 = (r & 3) * 64, t0 = (r >> 2) * 128;
                const unsigned short* A = z ? P.x_lo : P.x_hi;
                float* hp = z ? P.hp1 : P.hp0;
                const unsigned short* pa0 = A + (size_t)(t0 + r0t) * E + g * 8;
                const unsigned short* pa1 = A + (size_t)(t0 + r0t + 64) * E + g * 8;
                const unsigned short* pb0 = P.w1cat + (size_t)(n0 + r0t) * 2048 + g * 8;
                f32x4 acc[4][2];
#pragma unroll
                for (int s = 0; s < 4; ++s)
#pragma unroll
                    for (int t = 0; t < 2; ++t) acc[s][t] = (f32x4){0.f, 0.f, 0.f, 0.f};
                bf16x8 ra0 = *(const bf16x8*)(pa0);
                bf16x8 ra1 = *(const bf16x8*)(pa1);
                bf16x8 rb0 = *(const bf16x8*)(pb0);
                __syncthreads();                 // smem reuse guard
                *(bf16x8*)&As[r0t * 32 + gsl * 8] = ra0;
                *(bf16x8*)&As[(r0t + 64) * 32 + gsl * 8] = ra1;
                *(bf16x8*)&Bs[r0t * 32 + gsl * 8] = rb0;
                int k0 = 0;
                while (true) {
                    __syncthreads();
                    const int kn = k0 + 32;
                    if (kn < 2048) {
                        ra0 = *(const bf16x8*)(pa0 + (kn & 1023));
                        ra1 = *(const bf16x8*)(pa1 + (kn & 1023));
                        rb0 = *(const bf16x8*)(pb0 + kn);
                    }
                    bf16x8 af[4], bf[2];
#pragma unroll
                    for (int s = 0; s < 4; ++s) af[s] = *(const bf16x8*)&As[ldso(wm + s * 16 + lm, q)];
#pragma unroll
                    for (int t = 0; t < 2; ++t) bf[t] = *(const bf16x8*)&Bs[ldso(wn + t * 16 + lm, q)];
#pragma unroll
                    for (int s = 0; s < 4; ++s)
#pragma unroll
                        for (int t = 0; t < 2; ++t)
                            acc[s][t] = __builtin_amdgcn_mfma_f32_16x16x32_bf16(af[s], bf[t], acc[s][t], 0, 0, 0);
                    if (kn >= 2048) break;
                    __syncthreads();
                    *(bf16x8*)&As[r0t * 32 + gsl * 8] = ra0;
                    *(bf16x8*)&As[(r0t + 64) * 32 + gsl * 8] = ra1;
                    *(bf16x8*)&Bs[r0t * 32 + gsl * 8] = rb0;
                    k0 = kn;
                }
#pragma unroll
                for (int s = 0; s < 4; ++s)
#pragma unroll
                    for (int t = 0; t < 2; ++t)
#pragma unroll
                        for (int rg = 0; rg < 4; ++rg) {
                            int rl = wm + s * 16 + q * 4 + rg;
                            int c  = wn + t * 16 + lm;
                            hp[(size_t)(t0 + rl) * GH + n0 + c] = acc[s][t][rg];
                        }
            } else {
                int b = u - 512;
                if (b >= 6144) {                  // fl_dw [E][16] -> fl_dwT [16][E]
                    int idx = (b - 6144) * 256 + tid;
                    P.fl_dwT[idx] = P.fl_dw[(idx & (E - 1)) * 16 + (idx >> 10)];
                    continue;
                }
                const float* src; unsigned short* dst; int C, R, nbx;
                if (b < 2048)      { src = P.dfc_w;   dst = P.dfc_wt; R = 1024; C = 2048; nbx = 64; }
                else if (b < 4096) { src = P.dproj_w; dst = P.dpj_wt; R = 2048; C = 1024; nbx = 32; b -= 2048; }
                else if (b < 5120) { src = P.sfc_w;   dst = P.sfc_wt; R = 1024; C = 1024; nbx = 32; b -= 4096; }
                else               { src = P.sproj_w; dst = P.spj_wt; R = 1024; C = 1024; nbx = 32; b -= 5120; }
                const int c0 = (b % nbx) * 32, r0 = (b / nbx) * 32;
                __syncthreads();
#pragma unroll
                for (int i = 0; i < 4; ++i)
                    tile[ty + i * 8][tx] = src[(size_t)(r0 + ty + i * 8) * C + c0 + tx];
                __syncthreads();
#pragma unroll
                for (int i = 0; i < 4; ++i)
                    dst[(size_t)(c0 + ty + i * 8) * R + r0 + tx] = f2bf(tile[tx][ty + i * 8]);
            }
        }
    }
    grid.sync();

    //================ Phase C: finalize (256 units x 32 tokens) ==============
    {
        float* g2s  = (float*)smem;              // 1536 floats
        int* tokexp = (int*)(smem + 6144);       // 32 ints
        for (int u = blockIdx.x; u < 256; u += nb) {
            __syncthreads();
            for (int i = tid; i < GH * NEXP; i += 256) g2s[i] = P.gw2[i];
            __syncthreads();
            const int t0 = u * 32;
            const int tkg = tid >> 5, j = tid & 31;
#pragma unroll
            for (int rep = 0; rep < 4; ++rep) {
                const int t = t0 + tkg * 4 + rep;
                float p[NEXP] = {0.f, 0.f, 0.f, 0.f, 0.f, 0.f};
                const size_t base = (size_t)t * GH;
#pragma unroll
                for (int kk = 0; kk < 8; ++kk) {
                    const int k = j + kk * 32;
                    float hv = gelu_erf(P.hp0[base + k] + P.hp1[base + k] + P.gb1[k]);
                    const float* gr = &g2s[k * NEXP];
#pragma unroll
                    for (int m = 0; m < NEXP; ++m) p[m] += hv * gr[m];
                }
#pragma unroll
                for (int m = 0; m < NEXP; ++m) {
                    p[m] += __shfl_xor(p[m], 16, 64);
                    p[m] += __shfl_xor(p[m], 8, 64);
                    p[m] += __shfl_xor(p[m], 4, 64);
                    p[m] += __shfl_xor(p[m], 2, 64);
                    p[m] += __shfl_xor(p[m], 1, 64);
                }
                if (j == 0) {
                    float L[NEXP];
#pragma unroll
                    for (int m = 0; m < NEXP; ++m) L[m] = p[m] + P.gb2[m] + P.ebias[m];
                    float mx = L[0]; int am = 0;
#pragma unroll
                    for (int m = 1; m < NEXP; ++m) { if (L[m] > mx) { mx = L[m]; am = m; } }
                    float S = 0.f;
#pragma unroll
                    for (int m = 0; m < NEXP; ++m) S += expf(L[m] - mx);
                    float pt = 1.f / S;
                    P.scale[t] = P.pm_alpha[0] * (pt / (pt + 1e-9f));
                    P.eid[t] = am;
                    tokexp[tkg * 4 + rep] = am;
                }
            }
            __syncthreads();
            if (tid < NEXP) {
                int cnt = 0;
#pragma unroll
                for (int i = 0; i < 32; ++i) cnt += (tokexp[i] == tid);
                if (cnt) {
                    int bbase = atomicAdd(&P.counts[tid], cnt);
                    int pos = 0;
#pragma unroll
                    for (int i = 0; i < 32; ++i)
                        if (tokexp[i] == tid) P.tlist[tid * NTOK + bbase + (pos++)] = t0 + i;
                }
            }
        }
    }
    grid.sync();

    //================ Phase D: gemm1 (64x64 tiles, 1536 units) ===============
    {
        const int wm = (wvi & 1) * 32, wn = (wvi >> 1) * 32;
        const int lm = lane & 15, q = lane >> 4;
        const int r0t = tid >> 2, gsl = tid & 3;
        const int g = gsl ^ ((r0t >> 1) & 3);
        unsigned short* As = (unsigned short*)smem;        // 64x32
        unsigned short* Bs = As + 64 * 32;                 // 64x32
        int* toks = (int*)(Bs + 64 * 32);
        for (int u = blockIdx.x; u < 1536; u += nb) {
            int z, n0, i0;
            if (u < 1024) { z = 0; n0 = (u & 31) * 64; i0 = (u >> 5) * 64; }
            else { int v = u - 1024; z = 1; n0 = (v & 15) * 64; i0 = (v >> 4) * 64; }
            const int cnt = P.counts[z];
            if (i0 >= cnt) continue;
            const int N = z ? 1024 : 2048;
            const unsigned short* Bz = z ? P.sfc_wt : P.dfc_wt;
            const float* bias = z ? P.sfc_b : P.dfc_b;
            unsigned short* Hz = z ? P.h2 : P.h1;
            __syncthreads();
            if (tid < 64) toks[tid] = P.tlist[z * NTOK + min(i0 + tid, cnt - 1)];
            __syncthreads();
            const unsigned short* pa = P.x_hi + (size_t)toks[r0t] * E + g * 8;
            const unsigned short* pb = Bz + (size_t)(n0 + r0t) * E + g * 8;
            f32x4 acc[2][2];
#pragma unroll
            for (int s = 0; s < 2; ++s)
#pragma unroll
                for (int t = 0; t < 2; ++t) acc[s][t] = (f32x4){0.f, 0.f, 0.f, 0.f};
            bf16x8 ra = *(const bf16x8*)(pa);
            bf16x8 rb = *(const bf16x8*)(pb);
            *(bf16x8*)&As[r0t * 32 + gsl * 8] = ra;
            *(bf16x8*)&Bs[r0t * 32 + gsl * 8] = rb;
            int k0 = 0;
            while (true) {
                __syncthreads();
                const int kn = k0 + 32;
                if (kn < E) {
                    ra = *(const bf16x8*)(pa + kn);
                    rb = *(const bf16x8*)(pb + kn);
                }
                bf16x8 af[2], bf[2];
#pragma unroll
                for (int s = 0; s < 2; ++s) af[s] = *(const bf16x8*)&As[ldso(wm + s * 16 + lm, q)];
#pragma unroll
                for (int t = 0; t < 2; ++t) bf[t] = *(const bf16x8*)&Bs[ldso(wn + t * 16 + lm, q)];
#pragma unroll
                for (int s = 0; s < 2; ++s)
#pragma unroll
                    for (int t = 0; t < 2; ++t)
                        acc[s][t] = __builtin_amdgcn_mfma_f32_16x16x32_bf16(af[s], bf[t], acc[s][t], 0, 0, 0);
                if (kn >= E) break;
                __syncthreads();
                *(bf16x8*)&As[r0t * 32 + gsl * 8] = ra;
                *(bf16x8*)&Bs[r0t * 32 + gsl * 8] = rb;
                k0 = kn;
            }
#pragma unroll
            for (int s = 0; s < 2; ++s)
#pragma unroll
                for (int t = 0; t < 2; ++t)
#pragma unroll
                    for (int rg = 0; rg < 4; ++rg) {
                        int rl = wm + s * 16 + q * 4 + rg;
                        int gc = n0 + wn + t * 16 + lm;
                        float v = acc[s][t][rg] + bias[gc];
                        Hz[(size_t)(i0 + rl) * N + gc] = f2bf(gelu_erf(v));
                    }
        }
    }
    grid.sync();

    //================ Phase E: gemm2 (1024) + cheap (8192) ===================
    {
        const int wm = (wvi & 1) * 32, wn = (wvi >> 1) * 32;
        const int lm = lane & 15, q = lane >> 4;
        const int r0t = tid >> 2, gsl = tid & 3;
        const int g = gsl ^ ((r0t >> 1) & 3);
        unsigned short* As = (unsigned short*)smem;
        unsigned short* Bs = As + 64 * 32;
        int* toks = (int*)(Bs + 64 * 32);
        float* red = (float*)smem;
        float* gs  = red + 64;
        for (int u = blockIdx.x; u < 1024 + NTOK; u += nb) {
            if (u < 1024) {
                const int z = u >> 9, r = u & 511;
                const int n0 = (r & 15) * 64, i0 = (r >> 4) * 64;
                const int cnt = P.counts[z];
                if (i0 >= cnt) continue;
                const int rows = min(64, cnt - i0);
                const int K = z ? 1024 : 2048;
                const unsigned short* Az = z ? P.h2 : P.h1;
                const unsigned short* Bz = z ? P.spj_wt : P.dpj_wt;
                const float* bias = z ? P.sproj_b : P.dproj_b;
                __syncthreads();
                if (tid < 64) toks[tid] = P.tlist[z * NTOK + min(i0 + tid, cnt - 1)];
                __syncthreads();
                const unsigned short* pa = Az + (size_t)(i0 + r0t) * K + g * 8;
                const unsigned short* pb = Bz + (size_t)(n0 + r0t) * K + g * 8;
                f32x4 acc[2][2];
#pragma unroll
                for (int s = 0; s < 2; ++s)
#pragma unroll
                    for (int t = 0; t < 2; ++t) acc[s][t] = (f32x4){0.f, 0.f, 0.f, 0.f};
                bf16x8 ra = *(const bf16x8*)(pa);
                bf16x8 rb = *(const bf16x8*)(pb);
                *(bf16x8*)&As[r0t * 32 + gsl * 8] = ra;
                *(bf16x8*)&Bs[r0t * 32 + gsl * 8] = rb;
                int k0 = 0;
                while (true) {
                    __syncthreads();
                    const int kn = k0 + 32;
                    if (kn < K) {
                        ra = *(const bf16x8*)(pa + kn);
                        rb = *(const bf16x8*)(pb + kn);
                    }
                    bf16x8 af[2], bf[2];
#pragma unroll
                    for (int s = 0; s < 2; ++s) af[s] = *(const bf16x8*)&As[ldso(wm + s * 16 + lm, q)];
#pragma unroll
                    for (int t = 0; t < 2; ++t) bf[t] = *(const bf16x8*)&Bs[ldso(wn + t * 16 + lm, q)];
#pragma unroll
                    for (int s = 0; s < 2; ++s)
#pragma unroll
                        for (int t = 0; t < 2; ++t)
                            acc[s][t] = __builtin_amdgcn_mfma_f32_16x16x32_bf16(af[s], bf[t], acc[s][t], 0, 0, 0);
                    if (kn >= K) break;
                    __syncthreads();
                    *(bf16x8*)&As[r0t * 32 + gsl * 8] = ra;
                    *(bf16x8*)&Bs[r0t * 32 + gsl * 8] = rb;
                    k0 = kn;
                }
#pragma unroll
                for (int s = 0; s < 2; ++s)
#pragma unroll
                    for (int t = 0; t < 2; ++t)
#pragma unroll
                        for (int rg = 0; rg < 4; ++rg) {
                            int rl = wm + s * 16 + q * 4 + rg;
                            if (rl < rows) {
                                int gc = n0 + wn + t * 16 + lm;
                                int tok = toks[rl];
                                P.out[(size_t)tok * E + gc] = P.scale[tok] * (acc[s][t][rg] + bias[gc]);
                            }
                        }
            } else {
                const int tok = u - 1024;
                const int e = P.eid[tok];
                if (e < 2) continue;
                __syncthreads();
                const int k4 = tid * 4;
                const float4 xv = *reinterpret_cast<const float4*>(&P.x[(size_t)tok * E + k4]);
                const float sc = P.scale[tok];
                const int wid = tid >> 6;
                float4 o;
                if (e == 2 || e == 3) {
                    const int n = (e == 2) ? 2 : 4;
                    const float* w    = (e == 2) ? P.p2_w : P.p4_w;
                    const float* v    = (e == 2) ? P.p2_v : P.p4_v;
                    const float* al   = (e == 2) ? P.p2_alpha : P.p4_alpha;
                    const float* b    = (e == 2) ? P.p2_b : P.p4_b;
                    const float* bias = (e == 2) ? P.p2_bias : P.p4_bias;
                    for (int j = 0; j < n; ++j) {
                        float val = dot4(xv, *reinterpret_cast<const float4*>(&w[j * E + k4]));
                        for (int off = 32; off > 0; off >>= 1) val += __shfl_down(val, off, 64);
                        if (lane == 0) red[j * 4 + wid] = val;
                    }
                    __syncthreads();
                    if (tid < n) {
                        float s = red[tid * 4] + red[tid * 4 + 1] + red[tid * 4 + 2] + red[tid * 4 + 3] + b[tid];
                        gs[tid] = al[tid] * gelu_erf(s);
                    }
                    __syncthreads();
                    o = *reinterpret_cast<const float4*>(&bias[k4]);
                    for (int j = 0; j < n; ++j) {
                        float4 vv = *reinterpret_cast<const float4*>(&v[j * E + k4]);
                        float gj = gs[j];
                        o.x += gj * vv.x; o.y += gj * vv.y; o.z += gj * vv.z; o.w += gj * vv.w;
                    }
                } else if (e == 4) {
                    float val = dot4(xv, *reinterpret_cast<const float4*>(&P.rg_u[k4]));
                    for (int off = 32; off > 0; off >>= 1) val += __shfl_down(val, off, 64);
                    if (lane == 0) red[wid] = val;
                    __syncthreads();
                    float s = red[0] + red[1] + red[2] + red[3] + P.rg_b[0];
                    float sg = 1.f / (1.f + expf(-s));
                    float4 av = *reinterpret_cast<const float4*>(&P.rg_a[k4]);
                    float4 bv = *reinterpret_cast<const float4*>(&P.rg_bias[k4]);
                    o.x = sg * xv.x * av.x + bv.x;
                    o.y = sg * xv.y * av.y + bv.y;
                    o.z = sg * xv.z * av.z + bv.z;
                    o.w = sg * xv.w * av.w + bv.w;
                } else {  // FiLM
#pragma unroll
                    for (int j = 0; j < 16; ++j) {
                        float val = dot4(xv, *reinterpret_cast<const float4*>(&P.fl_dwT[j * E + k4]));
                        for (int off = 32; off > 0; off >>= 1) val += __shfl_down(val, off, 64);
                        if (lane == 0) red[j * 4 + wid] = val;
                    }
                    __syncthreads();
                    if (tid < 16)
                        gs[tid] = gelu_erf(red[tid * 4] + red[tid * 4 + 1] + red[tid * 4 + 2] + red[tid * 4 + 3] + P.fl_db[tid]);
                    __syncthreads();
                    float4 ga = *reinterpret_cast<const float4*>(&P.fl_ub[k4]);
                    float4 be = *reinterpret_cast<const float4*>(&P.fl_ub[E + k4]);
#pragma unroll
                    for (int j = 0; j < 16; ++j) {
                        float tj = gs[j];
                        float4 ug = *reinterpret_cast<const float4*>(&P.fl_uw[(size_t)j * 2 * E + k4]);
                        float4 ub = *reinterpret_cast<const float4*>(&P.fl_uw[(size_t)j * 2 * E + E + k4]);
                        ga.x += tj * ug.x; ga.y += tj * ug.y; ga.z += tj * ug.z; ga.w += tj * ug.w;
                        be.x += tj * ub.x; be.y += tj * ub.y; be.z += tj * ub.z; be.w += tj * ub.w;
                    }
                    o.x = ga.x * xv.x + be.x;
                    o.y = ga.y * xv.y + be.y;
                    o.z = ga.z * xv.z + be.z;
                    o.w = ga.w * xv.w + be.w;
                }
                o.x *= sc; o.y *= sc; o.z *= sc; o.w *= sc;
                *reinterpret_cast<float4*>(&P.out[(size_t)tok * E + k4]) = o;
            }
        }
    }
}

extern "C" void kernel_launch(void* const* d_in, const int* in_sizes, int n_in,
                              void* d_out, int out_size, void* d_ws, size_t ws_size,
                              hipStream_t stream) {
    MoeParams P;
    P.x        = (const float*)d_in[0];
    P.gw1      = (const float*)d_in[1];
    P.gb1      = (const float*)d_in[2];
    P.gw2      = (const float*)d_in[3];
    P.gb2      = (const float*)d_in[4];
    P.ebias    = (const float*)d_in[5];
    P.pm_alpha = (const float*)d_in[6];
    P.dfc_w    = (const float*)d_in[7];
    P.dfc_b    = (const float*)d_in[8];
    P.dproj_w  = (const float*)d_in[9];
    P.dproj_b  = (const float*)d_in[10];
    P.sfc_w    = (const float*)d_in[11];
    P.sfc_b    = (const float*)d_in[12];
    P.sproj_w  = (const float*)d_in[13];
    P.sproj_b  = (const float*)d_in[14];
    P.p2_w     = (const float*)d_in[15];
    P.p2_v     = (const float*)d_in[16];
    P.p2_alpha = (const float*)d_in[17];
    P.p2_b     = (const float*)d_in[18];
    P.p2_bias  = (const float*)d_in[19];
    P.p4_w     = (const float*)d_in[20];
    P.p4_v     = (const float*)d_in[21];
    P.p4_alpha = (const float*)d_in[22];
    P.p4_b     = (const float*)d_in[23];
    P.p4_bias  = (const float*)d_in[24];
    P.rg_u     = (const float*)d_in[25];
    P.rg_a     = (const float*)d_in[26];
    P.rg_b     = (const float*)d_in[27];
    P.rg_bias  = (const float*)d_in[28];
    P.fl_dw    = (const float*)d_in[29];
    P.fl_db    = (const float*)d_in[30];
    P.fl_uw    = (const float*)d_in[31];
    P.fl_ub    = (const float*)d_in[32];
    P.out = (float*)d_out;

    char* ws = (char*)d_ws;
    size_t off = 0;
    P.counts = (int*)(ws + off);            off += 256;
    P.scale  = (float*)(ws + off);          off += (size_t)NTOK * 4;
    P.tlist  = (int*)(ws + off);            off += (size_t)NEXP * NTOK * 4;
    P.eid    = (int*)(ws + off);            off += (size_t)NTOK * 4;
    P.fl_dwT = (float*)(ws + off);          off += (size_t)16 * E * 4;
    P.w1cat  = (unsigned short*)(ws + off); off += (size_t)GH * 2048 * 2;
    P.dfc_wt = (unsigned short*)(ws + off); off += (size_t)2048 * 1024 * 2;
    P.dpj_wt = (unsigned short*)(ws + off); off += (size_t)1024 * 2048 * 2;
    P.sfc_wt = (unsigned short*)(ws + off); off += (size_t)1024 * 1024 * 2;
    P.spj_wt = (unsigned short*)(ws + off); off += (size_t)1024 * 1024 * 2;
    P.x_hi   = (unsigned short*)(ws + off); off += (size_t)NTOK * E * 2;
    // Union region (32 MB): gate phase {x_lo, hp0, hp1} then expert phase {h1, h2}
    char* U = ws + off;
    P.x_lo = (unsigned short*)U;
    P.hp0  = (float*)(U + (size_t)16 * 1024 * 1024);
    P.hp1  = (float*)(U + (size_t)24 * 1024 * 1024);
    P.h1   = (unsigned short*)U;
    P.h2   = (unsigned short*)(U + (size_t)16 * 1024 * 1024);

    int maxb = 0;
    hipOccupancyMaxActiveBlocksPerMultiprocessor(&maxb, moe_mega_kernel, 256, 0);
    if (maxb < 1) maxb = 1;
    unsigned int nblk = (unsigned int)maxb * 256u;
    if (nblk > 1024u) nblk = 1024u;
    void* args[] = { (void*)&P };
    hipLaunchCooperativeKernel(moe_mega_kernel, dim3(nblk), dim3(256), args, 0, stream);
    (void)in_sizes; (void)n_in; (void)out_size; (void)ws_size;
}

// Round 12
// 296.303 us; speedup vs baseline: 2.2780x; 2.2780x over previous
//
#include <hip/hip_runtime.h>
#include <math.h>

// Top-1 MoE, 6-dispatch pipeline (r11 cooperative mega-kernel REVERTED:
// grid.sync cost 675us vs 298 -- dispatch boundaries are the cheaper sync).
//   memset -> prep -> gate_partial -> gate_finalize -> gemm1 -> gemm2+cheap.
// r12: all MFMA K-loops use LDS double-buffering (1 barrier/iter instead of
// 2); gate_partial tiles 64x64 (1024 blocks, r8/r10 more-blocks-wins).

#define E 1024
#define GH 256
#define NEXP 6
#define NTOK 8192

typedef __attribute__((ext_vector_type(8))) short bf16x8;
typedef __attribute__((ext_vector_type(4))) float f32x4;

__device__ __forceinline__ float gelu_erf(float v) {
    return 0.5f * v * (1.0f + erff(v * 0.70710678118654752440f));
}

__device__ __forceinline__ unsigned short f2bf(float f) {
    union { float f; unsigned u; } c; c.f = f;
    unsigned u = c.u;
    u += 0x7fffu + ((u >> 16) & 1u);   // RNE
    return (unsigned short)(u >> 16);
}

__device__ __forceinline__ float bf2f(unsigned short h) {
    union { unsigned u; float f; } c; c.u = ((unsigned)h) << 16;
    return c.f;
}

__device__ __forceinline__ float dot4(float4 a, float4 b) {
    return a.x * b.x + a.y * b.y + a.z * b.z + a.w * b.w;
}

// LDS tile addressing (ushort units): row stride 32 (=64B), k-group XOR swizzle.
__device__ __forceinline__ int ldso(int row, int q) {
    return row * 32 + ((q ^ ((row >> 1) & 3)) << 3);
}

// ---------------- prep: convert + all transposes, one kernel ----------------
__global__ __launch_bounds__(256)
void prep_kernel(const float* __restrict__ x, unsigned short* __restrict__ xh,
                 unsigned short* __restrict__ xl,
                 const float* __restrict__ gw1, unsigned short* __restrict__ w1cat,
                 const float* __restrict__ fl_dw, float* __restrict__ fl_dwT,
                 const float* __restrict__ dfc_w, unsigned short* __restrict__ dfc_wt,
                 const float* __restrict__ dproj_w, unsigned short* __restrict__ dpj_wt,
                 const float* __restrict__ sfc_w, unsigned short* __restrict__ sfc_wt,
                 const float* __restrict__ sproj_w, unsigned short* __restrict__ spj_wt) {
    __shared__ float tile[32][33];
    const int tid = threadIdx.x;
    const int tx = tid & 31, ty = tid >> 5;
    int b = blockIdx.x;
    if (b < 2048) {                       // x -> x_hi + x_lo
        const int n4 = NTOK * E / 4;
        for (int i = b * 256 + tid; i < n4; i += 2048 * 256) {
            float4 v = reinterpret_cast<const float4*>(x)[i];
            ushort4 h, l;
            h.x = f2bf(v.x); l.x = f2bf(v.x - bf2f(h.x));
            h.y = f2bf(v.y); l.y = f2bf(v.y - bf2f(h.y));
            h.z = f2bf(v.z); l.z = f2bf(v.z - bf2f(h.z));
            h.w = f2bf(v.w); l.w = f2bf(v.w - bf2f(h.w));
            reinterpret_cast<ushort4*>(xh)[i] = h;
            reinterpret_cast<ushort4*>(xl)[i] = l;
        }
        return;
    }
    b -= 2048;
    if (b < 256) {                        // gw1 [E][GH] -> w1cat [GH][hi|lo]
        const int c0 = (b & 7) * 32, r0 = (b >> 3) * 32;
#pragma unroll
        for (int i = 0; i < 4; ++i)
            tile[ty + i * 8][tx] = gw1[(size_t)(r0 + ty + i * 8) * GH + c0 + tx];
        __syncthreads();
#pragma unroll
        for (int i = 0; i < 4; ++i) {
            float v = tile[tx][ty + i * 8];
            unsigned short h = f2bf(v);
            size_t row = (size_t)(c0 + ty + i * 8) * 2048;
            w1cat[row + r0 + tx] = h;
            w1cat[row + 1024 + r0 + tx] = f2bf(v - bf2f(h));
        }
        return;
    }
    b -= 256;
    if (b < 64) {                         // fl_dw [E][16] -> fl_dwT [16][E]
        int idx = b * 256 + tid;
        int j = idx >> 10, k = idx & (E - 1);
        fl_dwT[idx] = fl_dw[k * 16 + j];
        return;
    }
    b -= 64;
    const float* src; unsigned short* dst; int R, C, nbx;
    if (b < 2048)      { src = dfc_w;   dst = dfc_wt; R = 1024; C = 2048; nbx = 64; }
    else if (b < 4096) { src = dproj_w; dst = dpj_wt; R = 2048; C = 1024; nbx = 32; b -= 2048; }
    else if (b < 5120) { src = sfc_w;   dst = sfc_wt; R = 1024; C = 1024; nbx = 32; b -= 4096; }
    else               { src = sproj_w; dst = spj_wt; R = 1024; C = 1024; nbx = 32; b -= 5120; }
    const int c0 = (b % nbx) * 32, r0 = (b / nbx) * 32;
#pragma unroll
    for (int i = 0; i < 4; ++i)
        tile[ty + i * 8][tx] = src[(size_t)(r0 + ty + i * 8) * C + c0 + tx];
    __syncthreads();
#pragma unroll
    for (int i = 0; i < 4; ++i)
        dst[(size_t)(c0 + ty + i * 8) * R + r0 + tx] = f2bf(tile[tx][ty + i * 8]);
}

// ------ gate partial GEMM: hp_z = A_z @ w1cat, 64x64 tiles, LDS dbuf -------
// Grid (GH/64=4, NTOK/64=128, 2) = 1024 blocks. 4 waves of 32x32.
__global__ __launch_bounds__(256)
void gate_partial_kernel(const unsigned short* __restrict__ xh,
                         const unsigned short* __restrict__ xl,
                         const unsigned short* __restrict__ w1cat,
                         float* __restrict__ hp0, float* __restrict__ hp1) {
    __shared__ __align__(16) unsigned short As[2][64 * 32];
    __shared__ __align__(16) unsigned short Bs[2][64 * 32];
    const int tid = threadIdx.x;
    const int t0 = blockIdx.y * 64, n0 = blockIdx.x * 64, z = blockIdx.z;
    const unsigned short* A = z ? xl : xh;
    float* hp = z ? hp1 : hp0;

    const int lane = tid & 63, wv = tid >> 6;
    const int wm = (wv & 1) * 32, wn = (wv >> 1) * 32;
    const int lm = lane & 15, q = lane >> 4;
    const int r0 = tid >> 2, gsl = tid & 3;
    const int g = gsl ^ ((r0 >> 1) & 3);
    const int so = r0 * 32 + gsl * 8;

    const unsigned short* pa = A + (size_t)(t0 + r0) * E + g * 8;
    const unsigned short* pb = w1cat + (size_t)(n0 + r0) * 2048 + g * 8;

    f32x4 acc[2][2];
#pragma unroll
    for (int s = 0; s < 2; ++s)
#pragma unroll
        for (int t = 0; t < 2; ++t) acc[s][t] = (f32x4){0.f, 0.f, 0.f, 0.f};

    bf16x8 ra = *(const bf16x8*)(pa);
    bf16x8 rb = *(const bf16x8*)(pb);
    *(bf16x8*)&As[0][so] = ra;
    *(bf16x8*)&Bs[0][so] = rb;

    int cur = 0, k0 = 0;
    while (true) {
        __syncthreads();                      // buf[cur] writes + prev reads done
        const int kn = k0 + 32;
        if (kn < 2048) {
            ra = *(const bf16x8*)(pa + (kn & 1023));
            rb = *(const bf16x8*)(pb + kn);
        }
        bf16x8 af[2], bf[2];
#pragma unroll
        for (int s = 0; s < 2; ++s) af[s] = *(const bf16x8*)&As[cur][ldso(wm + s * 16 + lm, q)];
#pragma unroll
        for (int t = 0; t < 2; ++t) bf[t] = *(const bf16x8*)&Bs[cur][ldso(wn + t * 16 + lm, q)];
#pragma unroll
        for (int s = 0; s < 2; ++s)
#pragma unroll
            for (int t = 0; t < 2; ++t)
                acc[s][t] = __builtin_amdgcn_mfma_f32_16x16x32_bf16(af[s], bf[t], acc[s][t], 0, 0, 0);
        if (kn >= 2048) break;
        *(bf16x8*)&As[cur ^ 1][so] = ra;
        *(bf16x8*)&Bs[cur ^ 1][so] = rb;
        cur ^= 1; k0 = kn;
    }
#pragma unroll
    for (int s = 0; s < 2; ++s)
#pragma unroll
        for (int t = 0; t < 2; ++t)
#pragma unroll
            for (int rg = 0; rg < 4; ++rg) {
                int rl = wm + s * 16 + q * 4 + rg;
                int c  = wn + t * 16 + lm;
                hp[(size_t)(t0 + rl) * GH + n0 + c] = acc[s][t][rg];
            }
}

// ------- finalize: h=gelu(hp0+hp1+gb1); logits=h@gw2; softmax/argmax --------
__global__ __launch_bounds__(256)
void gate_finalize_kernel(const float* __restrict__ hp0, const float* __restrict__ hp1,
                          const float* __restrict__ gb1, const float* __restrict__ gw2,
                          const float* __restrict__ gb2, const float* __restrict__ ebias,
                          const float* __restrict__ pm_alpha,
                          float* __restrict__ scale, int* __restrict__ counts,
                          int* __restrict__ tlist, int* __restrict__ eid) {
    __shared__ float hs[32][264];
    __shared__ float g2s[GH * NEXP];
    __shared__ int tokexp[32];
    const int tid = threadIdx.x;
    const int t0 = blockIdx.x * 32;
    for (int i = tid; i < GH * NEXP; i += 256) g2s[i] = gw2[i];
#pragma unroll
    for (int i = 0; i < 8; ++i) {
        int f4 = i * 256 + tid;
        int row = f4 >> 6, c4 = (f4 & 63) * 4;
        size_t base = (size_t)(t0 + row) * GH + c4;
        float4 a = *reinterpret_cast<const float4*>(&hp0[base]);
        float4 b = *reinterpret_cast<const float4*>(&hp1[base]);
        float4 o;
        o.x = gelu_erf(a.x + b.x + gb1[c4 + 0]);
        o.y = gelu_erf(a.y + b.y + gb1[c4 + 1]);
        o.z = gelu_erf(a.z + b.z + gb1[c4 + 2]);
        o.w = gelu_erf(a.w + b.w + gb1[c4 + 3]);
        *reinterpret_cast<float4*>(&hs[row][c4]) = o;
    }
    __syncthreads();
    const int t = tid >> 3, j = tid & 7;
    float p[NEXP] = {0.f, 0.f, 0.f, 0.f, 0.f, 0.f};
#pragma unroll 8
    for (int kk = 0; kk < 32; ++kk) {
        int k = j + kk * 8;
        float hv = hs[t][k];
        const float* gr = &g2s[k * NEXP];
#pragma unroll
        for (int m = 0; m < NEXP; ++m) p[m] += hv * gr[m];
    }
#pragma unroll
    for (int m = 0; m < NEXP; ++m) {
        p[m] += __shfl_xor(p[m], 4, 64);
        p[m] += __shfl_xor(p[m], 2, 64);
        p[m] += __shfl_xor(p[m], 1, 64);
    }
    if (j == 0) {
        float L[NEXP];
#pragma unroll
        for (int m = 0; m < NEXP; ++m) L[m] = p[m] + gb2[m] + ebias[m];
        float mx = L[0]; int am = 0;
#pragma unroll
        for (int m = 1; m < NEXP; ++m) { if (L[m] > mx) { mx = L[m]; am = m; } }
        float S = 0.f;
#pragma unroll
        for (int m = 0; m < NEXP; ++m) S += expf(L[m] - mx);
        float pt = 1.f / S;
        scale[t0 + t] = pm_alpha[0] * (pt / (pt + 1e-9f));
        eid[t0 + t] = am;
        tokexp[t] = am;
    }
    __syncthreads();
    if (tid < NEXP) {
        const int e = tid;
        int cnt = 0;
#pragma unroll
        for (int i = 0; i < 32; ++i) cnt += (tokexp[i] == e);
        if (cnt) {
            int base = atomicAdd(&counts[e], cnt);
            int pos = 0;
#pragma unroll
            for (int i = 0; i < 32; ++i)
                if (tokexp[i] == e) tlist[e * NTOK + base + (pos++)] = t0 + i;
        }
    }
}

// ---------------- GEMM1: gather x_hi -> gelu -> packed bf16 h ---------------
// 64x64 tiles, 4 waves of 32x32, LDS double buffer.
__global__ __launch_bounds__(256)
void moe_gemm1_kernel(const unsigned short* __restrict__ xh,
                      const unsigned short* __restrict__ B0, const unsigned short* __restrict__ B1,
                      const float* __restrict__ bias0, const float* __restrict__ bias1,
                      const int* __restrict__ counts, const int* __restrict__ tlist,
                      unsigned short* __restrict__ H0, unsigned short* __restrict__ H1) {
    const int z = blockIdx.z;
    const int N = z ? 1024 : 2048;
    const int cnt = counts[z];
    const int i0 = blockIdx.y * 64;
    const int n0 = blockIdx.x * 64;
    if (i0 >= cnt || n0 >= N) return;
    const unsigned short* Bz = z ? B1 : B0;
    const float* bias = z ? bias1 : bias0;

    __shared__ __align__(16) unsigned short As[2][64 * 32];
    __shared__ __align__(16) unsigned short Bs[2][64 * 32];
    __shared__ int toks[64];
    const int tid = threadIdx.x;
    if (tid < 64) toks[tid] = tlist[z * NTOK + min(i0 + tid, cnt - 1)];
    __syncthreads();

    const int lane = tid & 63, wv = tid >> 6;
    const int wm = (wv & 1) * 32, wn = (wv >> 1) * 32;
    const int lm = lane & 15, q = lane >> 4;
    const int r0 = tid >> 2, gsl = tid & 3;
    const int g = gsl ^ ((r0 >> 1) & 3);
    const int so = r0 * 32 + gsl * 8;

    const unsigned short* pa = xh + (size_t)toks[r0] * E + g * 8;
    const unsigned short* pb = Bz + (size_t)(n0 + r0) * E + g * 8;

    f32x4 acc[2][2];
#pragma unroll
    for (int s = 0; s < 2; ++s)
#pragma unroll
        for (int t = 0; t < 2; ++t) acc[s][t] = (f32x4){0.f, 0.f, 0.f, 0.f};

    bf16x8 ra = *(const bf16x8*)(pa);
    bf16x8 rb = *(const bf16x8*)(pb);
    *(bf16x8*)&As[0][so] = ra;
    *(bf16x8*)&Bs[0][so] = rb;

    int cur = 0, k0 = 0;
    while (true) {
        __syncthreads();
        const int kn = k0 + 32;
        if (kn < E) {
            ra = *(const bf16x8*)(pa + kn);
            rb = *(const bf16x8*)(pb + kn);
        }
        bf16x8 af[2], bf[2];
#pragma unroll
        for (int s = 0; s < 2; ++s) af[s] = *(const bf16x8*)&As[cur][ldso(wm + s * 16 + lm, q)];
#pragma unroll
        for (int t = 0; t < 2; ++t) bf[t] = *(const bf16x8*)&Bs[cur][ldso(wn + t * 16 + lm, q)];
#pragma unroll
        for (int s = 0; s < 2; ++s)
#pragma unroll
            for (int t = 0; t < 2; ++t)
                acc[s][t] = __builtin_amdgcn_mfma_f32_16x16x32_bf16(af[s], bf[t], acc[s][t], 0, 0, 0);
        if (kn >= E) break;
        *(bf16x8*)&As[cur ^ 1][so] = ra;
        *(bf16x8*)&Bs[cur ^ 1][so] = rb;
        cur ^= 1; k0 = kn;
    }
    unsigned short* Hz = z ? H1 : H0;
#pragma unroll
    for (int s = 0; s < 2; ++s)
#pragma unroll
        for (int t = 0; t < 2; ++t)
#pragma unroll
            for (int rg = 0; rg < 4; ++rg) {
                int rl = wm + s * 16 + q * 4 + rg;
                int gc = n0 + wn + t * 16 + lm;
                float v = acc[s][t][rg] + bias[gc];
                Hz[(size_t)(i0 + rl) * N + gc] = f2bf(gelu_erf(v));
            }
}

// -------- fused GEMM2 (experts 0/1 down-proj) + cheap experts (2..5) --------
// blocks [0,1024): gemm2 64x64 tile, LDS dbuf.
// blocks [1024, 1024+NTOK): cheap token b-1024, eid-gated, float4-vectorized.
__global__ __launch_bounds__(256)
void gemm2_cheap_kernel(const unsigned short* __restrict__ h1, const unsigned short* __restrict__ h2,
                        const unsigned short* __restrict__ dpj, const unsigned short* __restrict__ spj,
                        const float* __restrict__ dproj_b, const float* __restrict__ sproj_b,
                        const int* __restrict__ counts, const int* __restrict__ tlist,
                        const float* __restrict__ scale,
                        const float* __restrict__ x, const int* __restrict__ eid,
                        const float* __restrict__ p2_w, const float* __restrict__ p2_v,
                        const float* __restrict__ p2_alpha, const float* __restrict__ p2_b,
                        const float* __restrict__ p2_bias,
                        const float* __restrict__ p4_w, const float* __restrict__ p4_v,
                        const float* __restrict__ p4_alpha, const float* __restrict__ p4_b,
                        const float* __restrict__ p4_bias,
                        const float* __restrict__ rg_u, const float* __restrict__ rg_a,
                        const float* __restrict__ rg_b, const float* __restrict__ rg_bias,
                        const float* __restrict__ fl_dwT, const float* __restrict__ fl_db,
                        const float* __restrict__ fl_uw, const float* __restrict__ fl_ub,
                        float* __restrict__ out) {
    __shared__ __align__(16) char smem[2 * 64 * 32 * 2 * 2 + 64 * 4];  // 16.6 KB
    const int tid = threadIdx.x;
    const int bb = blockIdx.x;
    const int lane = tid & 63;

    if (bb < 1024) {
        const int z = bb >> 9;
        const int r = bb & 511;
        const int n0 = (r & 15) * 64;
        const int i0 = (r >> 4) * 64;
        const int K = z ? 1024 : 2048;
        const int cnt = counts[z];
        if (i0 >= cnt) return;
        const int rows = min(64, cnt - i0);
        const unsigned short* Az = z ? h2 : h1;
        const unsigned short* Bz = z ? spj : dpj;
        const float* bias = z ? sproj_b : dproj_b;

        unsigned short (*As)[64 * 32] = (unsigned short (*)[64 * 32])smem;
        unsigned short (*Bs)[64 * 32] = (unsigned short (*)[64 * 32])(smem + 2 * 64 * 32 * 2);
        int* toks = (int*)(smem + 2 * 64 * 32 * 2 * 2);
        if (tid < 64) toks[tid] = tlist[z * NTOK + min(i0 + tid, cnt - 1)];
        __syncthreads();

        const int wv = tid >> 6;
        const int wm = (wv & 1) * 32, wn = (wv >> 1) * 32;
        const int lm = lane & 15, q = lane >> 4;
        const int r0 = tid >> 2, gsl = tid & 3;
        const int g = gsl ^ ((r0 >> 1) & 3);
        const int so = r0 * 32 + gsl * 8;

        const unsigned short* pa = Az + (size_t)(i0 + r0) * K + g * 8;
        const unsigned short* pb = Bz + (size_t)(n0 + r0) * K + g * 8;

        f32x4 acc[2][2];
#pragma unroll
        for (int s = 0; s < 2; ++s)
#pragma unroll
            for (int t = 0; t < 2; ++t) acc[s][t] = (f32x4){0.f, 0.f, 0.f, 0.f};

        bf16x8 ra = *(const bf16x8*)(pa);
        bf16x8 rb = *(const bf16x8*)(pb);
        *(bf16x8*)&As[0][so] = ra;
        *(bf16x8*)&Bs[0][so] = rb;

        int cur = 0, k0 = 0;
        while (true) {
            __syncthreads();
            const int kn = k0 + 32;
            if (kn < K) {
                ra = *(const bf16x8*)(pa + kn);
                rb = *(const bf16x8*)(pb + kn);
            }
            bf16x8 af[2], bf[2];
#pragma unroll
            for (int s = 0; s < 2; ++s) af[s] = *(const bf16x8*)&As[cur][ldso(wm + s * 16 + lm, q)];
#pragma unroll
            for (int t = 0; t < 2; ++t) bf[t] = *(const bf16x8*)&Bs[cur][ldso(wn + t * 16 + lm, q)];
#pragma unroll
            for (int s = 0; s < 2; ++s)
#pragma unroll
                for (int t = 0; t < 2; ++t)
                    acc[s][t] = __builtin_amdgcn_mfma_f32_16x16x32_bf16(af[s], bf[t], acc[s][t], 0, 0, 0);
            if (kn >= K) break;
            *(bf16x8*)&As[cur ^ 1][so] = ra;
            *(bf16x8*)&Bs[cur ^ 1][so] = rb;
            cur ^= 1; k0 = kn;
        }
#pragma unroll
        for (int s = 0; s < 2; ++s)
#pragma unroll
            for (int t = 0; t < 2; ++t)
#pragma unroll
                for (int rg = 0; rg < 4; ++rg) {
                    int rl = wm + s * 16 + q * 4 + rg;
                    if (rl < rows) {
                        int gc = n0 + wn + t * 16 + lm;
                        int tok = toks[rl];
                        out[(size_t)tok * E + gc] = scale[tok] * (acc[s][t][rg] + bias[gc]);
                    }
                }
        return;
    }

    // ---- cheap experts: one block per token, float4-vectorized (k = tid*4) --
    const int tok = bb - 1024;
    const int e = eid[tok];
    if (e < 2) return;
    float* red = (float*)smem;          // [16][4]
    float* gs  = red + 64;              // 16
    const int k4 = tid * 4;
    const float4 xv = *reinterpret_cast<const float4*>(&x[(size_t)tok * E + k4]);
    const float sc = scale[tok];
    const int wid = tid >> 6;
    float4 o;

    if (e == 2 || e == 3) {
        const int n = (e == 2) ? 2 : 4;
        const float* w    = (e == 2) ? p2_w : p4_w;
        const float* v    = (e == 2) ? p2_v : p4_v;
        const float* al   = (e == 2) ? p2_alpha : p4_alpha;
        const float* b    = (e == 2) ? p2_b : p4_b;
        const float* bias = (e == 2) ? p2_bias : p4_bias;
        for (int j = 0; j < n; ++j) {
            float val = dot4(xv, *reinterpret_cast<const float4*>(&w[j * E + k4]));
            for (int off = 32; off > 0; off >>= 1) val += __shfl_down(val, off, 64);
            if (lane == 0) red[j * 4 + wid] = val;
        }
        __syncthreads();
        if (tid < n) {
            float s = red[tid * 4] + red[tid * 4 + 1] + red[tid * 4 + 2] + red[tid * 4 + 3] + b[tid];
            gs[tid] = al[tid] * gelu_erf(s);
        }
        __syncthreads();
        o = *reinterpret_cast<const float4*>(&bias[k4]);
        for (int j = 0; j < n; ++j) {
            float4 vv = *reinterpret_cast<const float4*>(&v[j * E + k4]);
            float gj = gs[j];
            o.x += gj * vv.x; o.y += gj * vv.y; o.z += gj * vv.z; o.w += gj * vv.w;
        }
    } else if (e == 4) {
        float val = dot4(xv, *reinterpret_cast<const float4*>(&rg_u[k4]));
        for (int off = 32; off > 0; off >>= 1) val += __shfl_down(val, off, 64);
        if (lane == 0) red[wid] = val;
        __syncthreads();
        float s = red[0] + red[1] + red[2] + red[3] + rg_b[0];
        float sg = 1.f / (1.f + expf(-s));
        float4 av = *reinterpret_cast<const float4*>(&rg_a[k4]);
        float4 bv = *reinterpret_cast<const float4*>(&rg_bias[k4]);
        o.x = sg * xv.x * av.x + bv.x;
        o.y = sg * xv.y * av.y + bv.y;
        o.z = sg * xv.z * av.z + bv.z;
        o.w = sg * xv.w * av.w + bv.w;
    } else {  // FiLM
#pragma unroll
        for (int j = 0; j < 16; ++j) {
            float val = dot4(xv, *reinterpret_cast<const float4*>(&fl_dwT[j * E + k4]));
            for (int off = 32; off > 0; off >>= 1) val += __shfl_down(val, off, 64);
            if (lane == 0) red[j * 4 + wid] = val;
        }
        __syncthreads();
        if (tid < 16)
            gs[tid] = gelu_erf(red[tid * 4] + red[tid * 4 + 1] + red[tid * 4 + 2] + red[tid * 4 + 3] + fl_db[tid]);
        __syncthreads();
        float4 ga = *reinterpret_cast<const float4*>(&fl_ub[k4]);
        float4 be = *reinterpret_cast<const float4*>(&fl_ub[E + k4]);
#pragma unroll
        for (int j = 0; j < 16; ++j) {
            float tj = gs[j];
            float4 ug = *reinterpret_cast<const float4*>(&fl_uw[(size_t)j * 2 * E + k4]);
            float4 ub = *reinterpret_cast<const float4*>(&fl_uw[(size_t)j * 2 * E + E + k4]);
            ga.x += tj * ug.x; ga.y += tj * ug.y; ga.z += tj * ug.z; ga.w += tj * ug.w;
            be.x += tj * ub.x; be.y += tj * ub.y; be.z += tj * ub.z; be.w += tj * ub.w;
        }
        o.x = ga.x * xv.x + be.x;
        o.y = ga.y * xv.y + be.y;
        o.z = ga.z * xv.z + be.z;
        o.w = ga.w * xv.w + be.w;
    }
    o.x *= sc; o.y *= sc; o.z *= sc; o.w *= sc;
    *reinterpret_cast<float4*>(&out[(size_t)tok * E + k4]) = o;
}

extern "C" void kernel_launch(void* const* d_in, const int* in_sizes, int n_in,
                              void* d_out, int out_size, void* d_ws, size_t ws_size,
                              hipStream_t stream) {
    const float* x        = (const float*)d_in[0];
    const float* gw1      = (const float*)d_in[1];
    const float* gb1      = (const float*)d_in[2];
    const float* gw2      = (const float*)d_in[3];
    const float* gb2      = (const float*)d_in[4];
    const float* ebias    = (const float*)d_in[5];
    const float* pm_alpha = (const float*)d_in[6];
    const float* dfc_w    = (const float*)d_in[7];
    const float* dfc_b    = (const float*)d_in[8];
    const float* dproj_w  = (const float*)d_in[9];
    const float* dproj_b  = (const float*)d_in[10];
    const float* sfc_w    = (const float*)d_in[11];
    const float* sfc_b    = (const float*)d_in[12];
    const float* sproj_w  = (const float*)d_in[13];
    const float* sproj_b  = (const float*)d_in[14];
    const float* p2_w     = (const float*)d_in[15];
    const float* p2_v     = (const float*)d_in[16];
    const float* p2_alpha = (const float*)d_in[17];
    const float* p2_b     = (const float*)d_in[18];
    const float* p2_bias  = (const float*)d_in[19];
    const float* p4_w     = (const float*)d_in[20];
    const float* p4_v     = (const float*)d_in[21];
    const float* p4_alpha = (const float*)d_in[22];
    const float* p4_b     = (const float*)d_in[23];
    const float* p4_bias  = (const float*)d_in[24];
    const float* rg_u     = (const float*)d_in[25];
    const float* rg_a     = (const float*)d_in[26];
    const float* rg_b     = (const float*)d_in[27];
    const float* rg_bias  = (const float*)d_in[28];
    const float* fl_dw    = (const float*)d_in[29];
    const float* fl_db    = (const float*)d_in[30];
    const float* fl_uw    = (const float*)d_in[31];
    const float* fl_ub    = (const float*)d_in[32];
    float* out = (float*)d_out;

    char* ws = (char*)d_ws;
    size_t off = 0;
    int*            counts = (int*)(ws + off);            off += 256;
    float*          scale  = (float*)(ws + off);          off += (size_t)NTOK * 4;
    int*            tlist  = (int*)(ws + off);            off += (size_t)NEXP * NTOK * 4;
    int*            eid    = (int*)(ws + off);            off += (size_t)NTOK * 4;
    float*          fl_dwT = (float*)(ws + off);          off += (size_t)16 * E * 4;
    unsigned short* w1cat  = (unsigned short*)(ws + off); off += (size_t)GH * 2048 * 2;
    unsigned short* dfc_wt = (unsigned short*)(ws + off); off += (size_t)2048 * 1024 * 2;
    unsigned short* dpj_wt = (unsigned short*)(ws + off); off += (size_t)1024 * 2048 * 2;
    unsigned short* sfc_wt = (unsigned short*)(ws + off); off += (size_t)1024 * 1024 * 2;
    unsigned short* spj_wt = (unsigned short*)(ws + off); off += (size_t)1024 * 1024 * 2;
    unsigned short* x_hi   = (unsigned short*)(ws + off); off += (size_t)NTOK * E * 2;
    // Union region (32 MB): gate phase {x_lo, hp0, hp1} then expert phase {h1, h2}
    char* U = ws + off;
    unsigned short* x_lo = (unsigned short*)U;                              // 16 MB
    float*          hp0  = (float*)(U + (size_t)16 * 1024 * 1024);          // 8 MB
    float*          hp1  = (float*)(U + (size_t)24 * 1024 * 1024);          // 8 MB
    unsigned short* h1   = (unsigned short*)U;                              // 16 MB (2048 x 2048)
    unsigned short* h2   = (unsigned short*)(U + (size_t)16 * 1024 * 1024); // 8 MB (2048 x 1024)

    hipMemsetAsync(counts, 0, 256, stream);
    prep_kernel<<<8512, 256, 0, stream>>>(x, x_hi, x_lo, gw1, w1cat, fl_dw, fl_dwT,
                                          dfc_w, dfc_wt, dproj_w, dpj_wt,
                                          sfc_w, sfc_wt, sproj_w, spj_wt);
    gate_partial_kernel<<<dim3(GH / 64, NTOK / 64, 2), 256, 0, stream>>>(x_hi, x_lo, w1cat, hp0, hp1);
    gate_finalize_kernel<<<NTOK / 32, 256, 0, stream>>>(hp0, hp1, gb1, gw2, gb2, ebias,
                                                        pm_alpha, scale, counts, tlist, eid);
    // y: 32 x 64-row tiles = 2048 rows (mean+20sigma of fixed multinomial counts)
    moe_gemm1_kernel<<<dim3(32, 32, 2), 256, 0, stream>>>(
        x_hi, dfc_wt, sfc_wt, dfc_b, sfc_b, counts, tlist, h1, h2);
    gemm2_cheap_kernel<<<1024 + NTOK, 256, 0, stream>>>(
        h1, h2, dpj_wt, spj_wt, dproj_b, sproj_b, counts, tlist, scale,
        x, eid,
        p2_w, p2_v, p2_alpha, p2_b, p2_bias,
        p4_w, p4_v, p4_alpha, p4_b, p4_bias,
        rg_u, rg_a, rg_b, rg_bias,
        fl_dwT, fl_db, fl_uw, fl_ub, out);
    (void)in_sizes; (void)n_in; (void)out_size; (void)ws_size;
}